// Round 11
// baseline (190.968 us; speedup 1.0000x reference)
//
#include <hip/hip_runtime.h>
#include <hip/hip_bf16.h>
#include <cstdint>

// Problem constants (fixed by the reference)
#define NB 4            // batch
#define NS 2048         // sequence
#define ND 512          // feature dim
#define NM 2048         // MAX_LEN (clamp M)
#define NV 4097         // table rows = 2M+1
#define NP 3000         // POS_MAX
#define RSW 3080        // rs table row stride
#define EBI_KB 129      // kb tiles per dt (EVW=4128 / 32)
#define HTI_BATCH_BYTES (2 * 256 * 1024)   // 2 phases x 256 tblk x 1KB

typedef __bf16 bf16x8 __attribute__((ext_vector_type(8)));
typedef float f32x4 __attribute__((ext_vector_type(4)));

__device__ __forceinline__ unsigned short f2bf(float f) {
  union { __bf16 b; unsigned short u; } cv;
  cv.b = (__bf16)f;
  return cv.u;
}

__device__ __forceinline__ int lbound_dev(const int* a, int n, int key) {
  int lo = 0, hi = n;
  while (lo < hi) { int mid = (lo + hi) >> 1; if (a[mid] < key) lo = mid + 1; else hi = mid; }
  return lo;  // count of elements < key
}

// ---------- k1: per-batch histogram (LDS atomics, 1024 threads/block) ----------
__global__ void k1_hist(const int* __restrict__ pos, unsigned int* __restrict__ hist) {
  __shared__ unsigned int h[NP];
  int b = blockIdx.x, tid = threadIdx.x;
  for (int i = tid; i < NP; i += 1024) h[i] = 0u;
  __syncthreads();
  const int* pb = pos + b * NS;
  if (tid < NS) atomicAdd(&h[pb[tid]], 1u);
  if (tid + 1024 < NS) atomicAdd(&h[pb[tid + 1024]], 1u);
  __syncthreads();
  unsigned int* hb = hist + b * NP;
  for (int i = tid; i < NP; i += 1024) hb[i] = h[i];
}

// ---------- k_prep: fused prep (one launch) ----------
// blocks [0,52):    rs[b][t] = #{ j : pos_j < t }
// blocks [52,564):  HTI[b][p][tb][l*8+e] = bf16(hist[5104 + (l&15) - tb*32 - p*16 - (l>>4)*8 - e])
//                   (frag-ready reversed-histogram: one wave-coalesced 1KB block per (tb,p))
// blocks [564,1084): EBI[dt][kb][l*8+e] = bf16(embz[kb*32 + (l>>4)*8 + e][dt*16 + (l&15)])
//                   embz = emb with rows 0, 4096 (clamp rows, handled fp32 in epilogue) zeroed
__global__ void k_prep(const int* __restrict__ pos, const unsigned int* __restrict__ hist,
                       const float* __restrict__ emb, unsigned short* __restrict__ HTI,
                       unsigned short* __restrict__ EBI, int* __restrict__ rs) {
  __shared__ float tile[64][65];
  int blk = blockIdx.x, tid = threadIdx.x;
  if (blk < 52) {
    int b = blk & 3, chunk = blk >> 2;
    int t = chunk * 256 + tid;
    if (t <= 3072) rs[b * RSW + t] = lbound_dev(pos + b * NS, NS, t);
    return;
  }
  if (blk < 564) {
    int idx = (blk - 52) * 256 + tid;            // 131072 = 4b x 2p x 256tb x 64l
    int l = idx & 63;
    int tb = (idx >> 6) & 255;
    int p = (idx >> 14) & 1;
    int bb = idx >> 15;
    const unsigned int* hbt = hist + bb * NP;
    int base = 5104 + (l & 15) - tb * 32 - p * 16 - ((l >> 4) * 8);
    union { unsigned short us[8]; uint4 v4; } pk;
#pragma unroll
    for (int e = 0; e < 8; ++e) {
      int ii = base - e;
      float f = (ii >= 0 && ii < NP) ? (float)hbt[ii] : 0.0f;
      pk.us[e] = f2bf(f);
    }
    *(uint4*)(HTI + ((size_t)(bb * 2 + p) * 256 + tb) * 512 + l * 8) = pk.v4;
    return;
  }
  {
    int blk2 = blk - 564;                        // 520 = 65 v-tiles x 8 d-tiles
    int v0 = (blk2 % 65) * 64, d0 = (blk2 / 65) * 64;
    int c = tid & 63, r0 = tid >> 6;
#pragma unroll
    for (int k = 0; k < 16; ++k) {
      int r = k * 4 + r0;
      int v = v0 + r;
      float val = 0.f;
      if (v < NV && v != 0 && v != (NV - 1)) val = emb[(size_t)v * ND + d0 + c];
      tile[r][c] = val;
    }
    __syncthreads();
#pragma unroll
    for (int rep = 0; rep < 2; ++rep) {
      int tile_id = rep * 4 + (tid >> 6);        // 8 (dt_loc,kb_loc) tiles per block
      int l = tid & 63;
      int kb_loc = tile_id >> 2, dt_loc = tile_id & 3;
      int kb = (v0 >> 5) + kb_loc, dt = (d0 >> 4) + dt_loc;
      if (kb < EBI_KB) {
        union { unsigned short us[8]; uint4 v4; } pk;
#pragma unroll
        for (int e = 0; e < 8; ++e)
          pk.us[e] = f2bf(tile[kb_loc * 32 + ((l >> 4) * 8) + e][dt_loc * 16 + (l & 15)]);
        *(uint4*)(EBI + ((size_t)dt * EBI_KB + kb) * 512 + l * 8) = pk.v4;
      }
    }
  }
}

// ---------- k4: barrier-free direct-to-register Toeplitz GEMM + scatter epilogue ----------
// r8 structure (proven 96us): 32q x 64d wave tile, acc[2][4], 8 MFMA + 6 coalesced
// 1KB loads/step, no LDS, no barriers. Changes vs r8 (latency-bound diagnosis, r10):
//   * depth-4 register pipeline (4 named sets, 3-step lookahead ~175cyc/wave;
//     x3 waves/SIMD covers worst-case L2 latency)
//   * bijective XCD swizzle (768 blocks, 768%8==0) - r10 proved it halves FETCH_SIZE
#define LOADSET(sa0, sa1, sb0, sb1, sb2, sb3, tt)                                   \
  if ((tt) < nt) {                                                                  \
    int tof = (tt) * 1024 + vo;                                                     \
    sa0 = *(const bf16x8*)(hb + (size_t)(cA0 + tof));                               \
    sa1 = *(const bf16x8*)(hb + (size_t)(cA1 + tof));                               \
    sb0 = *(const bf16x8*)(eb + (size_t)(cB0 + tof));                               \
    sb1 = *(const bf16x8*)(eb + (size_t)(cB1 + tof));                               \
    sb2 = *(const bf16x8*)(eb + (size_t)(cB2 + tof));                               \
    sb3 = *(const bf16x8*)(eb + (size_t)(cB3 + tof));                               \
  }

#define MMSET(sa0, sa1, sb0, sb1, sb2, sb3)                                         \
  acc[0][0] = __builtin_amdgcn_mfma_f32_16x16x32_bf16(sa0, sb0, acc[0][0], 0, 0, 0);\
  acc[0][1] = __builtin_amdgcn_mfma_f32_16x16x32_bf16(sa0, sb1, acc[0][1], 0, 0, 0);\
  acc[0][2] = __builtin_amdgcn_mfma_f32_16x16x32_bf16(sa0, sb2, acc[0][2], 0, 0, 0);\
  acc[0][3] = __builtin_amdgcn_mfma_f32_16x16x32_bf16(sa0, sb3, acc[0][3], 0, 0, 0);\
  acc[1][0] = __builtin_amdgcn_mfma_f32_16x16x32_bf16(sa1, sb0, acc[1][0], 0, 0, 0);\
  acc[1][1] = __builtin_amdgcn_mfma_f32_16x16x32_bf16(sa1, sb1, acc[1][1], 0, 0, 0);\
  acc[1][2] = __builtin_amdgcn_mfma_f32_16x16x32_bf16(sa1, sb2, acc[1][2], 0, 0, 0);\
  acc[1][3] = __builtin_amdgcn_mfma_f32_16x16x32_bf16(sa1, sb3, acc[1][3], 0, 0, 0);

__global__ __launch_bounds__(256)
void k4_gemm(const unsigned short* __restrict__ HTI, const unsigned short* __restrict__ EBI,
             const int* __restrict__ rs, const float* __restrict__ x,
             const float* __restrict__ emb, float* __restrict__ out) {
  int tid = threadIdx.x, w = tid >> 6, lane = tid & 63;
  // bijective XCD swizzle: 768 blocks, XCD j gets flat ids [j*96,(j+1)*96)
  int flat = (blockIdx.x & 7) * 96 + (blockIdx.x >> 3);
  int qb = flat % 24;
  int rest = flat / 24;
  int db = rest & 7, b = rest >> 3;
  int Q0w = qb * 128 + w * 32;                   // waves q-stacked: B addrs shared -> L1/L2
  int D0w = db * 64;

  int v_lo = (Q0w > 951) ? ((Q0w - 951) & ~31) : 0;
  int v_hi = Q0w + 2080; if (v_hi > 4128) v_hi = 4128;
  int nt = (v_hi - v_lo) >> 5;                   // 64..95 (>= 65 actually; >= 4 needed)

  const char* hb = (const char*)HTI + (size_t)b * HTI_BATCH_BYTES;
  const char* eb = (const char*)EBI;

  // uniform per-wave byte-offset constants
  int S0 = 3056 - Q0w + v_lo;                    // mf=0 base elem (mult of 16, >=0)
  int S1 = S0 - 16;                              // mf=1
  int cA0 = (((S0 >> 4) & 1) * 256 + (S0 >> 5)) * 1024;
  int cA1 = (((S1 >> 4) & 1) * 256 + (S1 >> 5)) * 1024;
  int kb0 = v_lo >> 5, dt0 = D0w >> 4;
  int cB0 = ((dt0 + 0) * EBI_KB + kb0) * 1024;
  int cB1 = ((dt0 + 1) * EBI_KB + kb0) * 1024;
  int cB2 = ((dt0 + 2) * EBI_KB + kb0) * 1024;
  int cB3 = ((dt0 + 3) * EBI_KB + kb0) * 1024;
  int vo = lane * 16;

  f32x4 acc[2][4];
#pragma unroll
  for (int a1 = 0; a1 < 2; ++a1)
#pragma unroll
    for (int a2 = 0; a2 < 4; ++a2) { f32x4 z = {0.f, 0.f, 0.f, 0.f}; acc[a1][a2] = z; }

  bf16x8 a00, a01, b00, b01, b02, b03;
  bf16x8 a10, a11, b10, b11, b12, b13;
  bf16x8 a20, a21, b20, b21, b22, b23;
  bf16x8 a30, a31, b30, b31, b32, b33;

  LOADSET(a00, a01, b00, b01, b02, b03, 0);
  LOADSET(a10, a11, b10, b11, b12, b13, 1);
  LOADSET(a20, a21, b20, b21, b22, b23, 2);

  int t = 0;
  for (;;) {
    LOADSET(a30, a31, b30, b31, b32, b33, t + 3);
    MMSET(a00, a01, b00, b01, b02, b03);
    if (++t == nt) break;
    LOADSET(a00, a01, b00, b01, b02, b03, t + 3);
    MMSET(a10, a11, b10, b11, b12, b13);
    if (++t == nt) break;
    LOADSET(a10, a11, b10, b11, b12, b13, t + 3);
    MMSET(a20, a21, b20, b21, b22, b23);
    if (++t == nt) break;
    LOADSET(a20, a21, b20, b21, b22, b23, t + 3);
    MMSET(a30, a31, b30, b31, b32, b33);
    if (++t == nt) break;
  }

  // Epilogue: scatter each q-row to all i with pos_i == q (contiguous via rs)
  const int* rsb = rs + b * RSW;
  const float* xb = x + (size_t)b * NS * ND;
  float* outb = out + (size_t)b * NS * ND;
  int col = lane & 15, rb4 = (lane >> 4) * 4;
#pragma unroll
  for (int nf = 0; nf < 4; ++nf) {
    int dcol = D0w + nf * 16 + col;
    float e0v = emb[dcol];                          // emb row 0 (fp32, exact)
    float eMv = emb[(size_t)(NV - 1) * ND + dcol];  // emb row 2M
#pragma unroll
    for (int mf = 0; mf < 2; ++mf) {
#pragma unroll
      for (int j = 0; j < 4; ++j) {
        int q = Q0w + mf * 16 + rb4 + j;
        if (q >= NP) continue;
        int i0 = rsb[q], i1 = rsb[q + 1];
        if (i0 == i1) continue;
        int cge = (q >= NM) ? rsb[q - NM + 1] : 0;          // #{pos_j <= q-M}
        int cle = (q + NM < NP) ? (NS - rsb[q + NM]) : 0;   // #{pos_j >= q+M}
        float val = (acc[mf][nf][j] + (float)cge * eMv + (float)cle * e0v) * (1.0f / (float)NS);
        for (int i = i0; i < i1; ++i)
          outb[(size_t)i * ND + dcol] = xb[(size_t)i * ND + dcol] + val;
      }
    }
  }
}

extern "C" void kernel_launch(void* const* d_in, const int* in_sizes, int n_in,
                              void* d_out, int out_size, void* d_ws, size_t ws_size,
                              hipStream_t stream) {
  const float* x = (const float*)d_in[0];
  const float* emb = (const float*)d_in[1];
  const int* pos = (const int*)d_in[2];
  float* out = (float*)d_out;

  char* ws = (char*)d_ws;
  unsigned short* HTI = (unsigned short*)(ws);                // 4 x 512KB   = 2,097,152 B
  unsigned short* EBI = (unsigned short*)(ws + 2097152);      // 32x129x1KB  = 4,227,072 B
  unsigned int* hist = (unsigned int*)(ws + 6324224);         // 4*3000*4    = 48,000 B
  int* rs = (int*)(ws + 6372224);                             // 4*3080*4    = 49,280 B
  // total ws use ~6.2 MB

  hipLaunchKernelGGL(k1_hist, dim3(NB), dim3(1024), 0, stream, pos, hist);
  hipLaunchKernelGGL(k_prep, dim3(1084), dim3(256), 0, stream, pos, hist, emb, HTI, EBI, rs);
  hipLaunchKernelGGL(k4_gemm, dim3(768), dim3(256), 0, stream, HTI, EBI, rs, x, emb, out);
}

// Round 12
// 156.007 us; speedup vs baseline: 1.2241x; 1.2241x over previous
//
#include <hip/hip_runtime.h>
#include <hip/hip_bf16.h>
#include <cstdint>

// Problem constants (fixed by the reference)
#define NB 4            // batch
#define NS 2048         // sequence
#define ND 512          // feature dim
#define NM 2048         // MAX_LEN (clamp M)
#define NV 4097         // table rows = 2M+1
#define NP 3000         // POS_MAX
#define RSW 3080        // rs table row stride
#define EBI_KB 129      // kb tiles per dt (EVW=4128 / 32)
#define HTI_BATCH_BYTES (2 * 256 * 1024)   // 2 phases x 256 tblk x 1KB

typedef __bf16 bf16x8 __attribute__((ext_vector_type(8)));
typedef float f32x4 __attribute__((ext_vector_type(4)));

__device__ __forceinline__ unsigned short f2bf(float f) {
  union { __bf16 b; unsigned short u; } cv;
  cv.b = (__bf16)f;
  return cv.u;
}

__device__ __forceinline__ int lbound_dev(const int* a, int n, int key) {
  int lo = 0, hi = n;
  while (lo < hi) { int mid = (lo + hi) >> 1; if (a[mid] < key) lo = mid + 1; else hi = mid; }
  return lo;  // count of elements < key
}

// ---------- k_prep: ALL prep in one launch (no separate hist kernel) ----------
// blocks [0,52):    rs[b][t] = #{ j : pos_j < t }
// blocks [52,564):  HTI[b][p][tb][l*8+e] = bf16(hist[5104 + (l&15) - tb*32 - p*16 - (l>>4)*8 - e])
//                   each block recomputes its batch's 3000-bin histogram in LDS
//                   (2048 coalesced reads + LDS atomics — removes k1_hist + its dependency)
// blocks [564,1084): EBI[dt][kb][l*8+e] = bf16(embz[kb*32 + (l>>4)*8 + e][dt*16 + (l&15)])
//                   embz = emb with clamp rows 0, 4096 zeroed (handled fp32 in epilogue)
__global__ void k_prep(const int* __restrict__ pos, const float* __restrict__ emb,
                       unsigned short* __restrict__ HTI, unsigned short* __restrict__ EBI,
                       int* __restrict__ rs) {
  __shared__ float tile[64][65];
  __shared__ unsigned int h[NP];
  int blk = blockIdx.x, tid = threadIdx.x;
  if (blk < 52) {
    int b = blk & 3, chunk = blk >> 2;
    int t = chunk * 256 + tid;
    if (t <= 3072) rs[b * RSW + t] = lbound_dev(pos + b * NS, NS, t);
    return;
  }
  if (blk < 564) {
    int idx = (blk - 52) * 256 + tid;            // 131072 = 4b x 2p x 256tb x 64l
    int bb = idx >> 15;                          // uniform per block (128 blocks/batch)
    for (int i = tid; i < NP; i += 256) h[i] = 0u;
    __syncthreads();
    const int* pb = pos + bb * NS;
    for (int i = tid; i < NS; i += 256) atomicAdd(&h[pb[i]], 1u);
    __syncthreads();
    int l = idx & 63;
    int tb = (idx >> 6) & 255;
    int p = (idx >> 14) & 1;
    int base = 5104 + (l & 15) - tb * 32 - p * 16 - ((l >> 4) * 8);
    union { unsigned short us[8]; uint4 v4; } pk;
#pragma unroll
    for (int e = 0; e < 8; ++e) {
      int ii = base - e;
      float f = (ii >= 0 && ii < NP) ? (float)h[ii] : 0.0f;
      pk.us[e] = f2bf(f);
    }
    *(uint4*)(HTI + ((size_t)(bb * 2 + p) * 256 + tb) * 512 + l * 8) = pk.v4;
    return;
  }
  {
    int blk2 = blk - 564;                        // 520 = 65 v-tiles x 8 d-tiles
    int v0 = (blk2 % 65) * 64, d0 = (blk2 / 65) * 64;
    int c = tid & 63, r0 = tid >> 6;
#pragma unroll
    for (int k = 0; k < 16; ++k) {
      int r = k * 4 + r0;
      int v = v0 + r;
      float val = 0.f;
      if (v < NV && v != 0 && v != (NV - 1)) val = emb[(size_t)v * ND + d0 + c];
      tile[r][c] = val;
    }
    __syncthreads();
#pragma unroll
    for (int rep = 0; rep < 2; ++rep) {
      int tile_id = rep * 4 + (tid >> 6);        // 8 (dt_loc,kb_loc) tiles per block
      int l = tid & 63;
      int kb_loc = tile_id >> 2, dt_loc = tile_id & 3;
      int kb = (v0 >> 5) + kb_loc, dt = (d0 >> 4) + dt_loc;
      if (kb < EBI_KB) {
        union { unsigned short us[8]; uint4 v4; } pk;
#pragma unroll
        for (int e = 0; e < 8; ++e)
          pk.us[e] = f2bf(tile[kb_loc * 32 + ((l >> 4) * 8) + e][dt_loc * 16 + (l & 15)]);
        *(uint4*)(EBI + ((size_t)dt * EBI_KB + kb) * 512 + l * 8) = pk.v4;
      }
    }
  }
}

// ---------- k4: barrier-free direct-to-register Toeplitz GEMM + scatter epilogue ----------
// EXACT r8 structure (best measured: 96us, 371 TF eff): 32q x 64d wave tile, acc[2][4],
// 8 MFMA + 6 coalesced 1KB loads/step, depth-2 register pipeline (3 named sets),
// no LDS, no barriers. ONLY delta vs r8: bijective XCD swizzle (768 = 8x96), which
// halved FETCH_SIZE in r10/r11 (33.5 -> 17.5 MB).
#define LOADSET(sa0, sa1, sb0, sb1, sb2, sb3, tt)                                   \
  if ((tt) < nt) {                                                                  \
    int tof = (tt) * 1024 + vo;                                                     \
    sa0 = *(const bf16x8*)(hb + (size_t)(cA0 + tof));                               \
    sa1 = *(const bf16x8*)(hb + (size_t)(cA1 + tof));                               \
    sb0 = *(const bf16x8*)(eb + (size_t)(cB0 + tof));                               \
    sb1 = *(const bf16x8*)(eb + (size_t)(cB1 + tof));                               \
    sb2 = *(const bf16x8*)(eb + (size_t)(cB2 + tof));                               \
    sb3 = *(const bf16x8*)(eb + (size_t)(cB3 + tof));                               \
  }

#define MMSET(sa0, sa1, sb0, sb1, sb2, sb3)                                         \
  acc[0][0] = __builtin_amdgcn_mfma_f32_16x16x32_bf16(sa0, sb0, acc[0][0], 0, 0, 0);\
  acc[0][1] = __builtin_amdgcn_mfma_f32_16x16x32_bf16(sa0, sb1, acc[0][1], 0, 0, 0);\
  acc[0][2] = __builtin_amdgcn_mfma_f32_16x16x32_bf16(sa0, sb2, acc[0][2], 0, 0, 0);\
  acc[0][3] = __builtin_amdgcn_mfma_f32_16x16x32_bf16(sa0, sb3, acc[0][3], 0, 0, 0);\
  acc[1][0] = __builtin_amdgcn_mfma_f32_16x16x32_bf16(sa1, sb0, acc[1][0], 0, 0, 0);\
  acc[1][1] = __builtin_amdgcn_mfma_f32_16x16x32_bf16(sa1, sb1, acc[1][1], 0, 0, 0);\
  acc[1][2] = __builtin_amdgcn_mfma_f32_16x16x32_bf16(sa1, sb2, acc[1][2], 0, 0, 0);\
  acc[1][3] = __builtin_amdgcn_mfma_f32_16x16x32_bf16(sa1, sb3, acc[1][3], 0, 0, 0);

__global__ __launch_bounds__(256)
void k4_gemm(const unsigned short* __restrict__ HTI, const unsigned short* __restrict__ EBI,
             const int* __restrict__ rs, const float* __restrict__ x,
             const float* __restrict__ emb, float* __restrict__ out) {
  int tid = threadIdx.x, w = tid >> 6, lane = tid & 63;
  // bijective XCD swizzle: 768 blocks, XCD j gets flat ids [j*96,(j+1)*96)
  int flat = (blockIdx.x & 7) * 96 + (blockIdx.x >> 3);
  int qb = flat % 24;
  int rest = flat / 24;
  int db = rest & 7, b = rest >> 3;
  int Q0w = qb * 128 + w * 32;                   // waves q-stacked: B addrs shared -> L1/L2
  int D0w = db * 64;

  int v_lo = (Q0w > 951) ? ((Q0w - 951) & ~31) : 0;
  int v_hi = Q0w + 2080; if (v_hi > 4128) v_hi = 4128;
  int nt = (v_hi - v_lo) >> 5;                   // 64..95

  const char* hb = (const char*)HTI + (size_t)b * HTI_BATCH_BYTES;
  const char* eb = (const char*)EBI;

  // uniform per-wave byte-offset constants
  int S0 = 3056 - Q0w + v_lo;                    // mf=0 base elem (mult of 16, >=0)
  int S1 = S0 - 16;                              // mf=1
  int cA0 = (((S0 >> 4) & 1) * 256 + (S0 >> 5)) * 1024;
  int cA1 = (((S1 >> 4) & 1) * 256 + (S1 >> 5)) * 1024;
  int kb0 = v_lo >> 5, dt0 = D0w >> 4;
  int cB0 = ((dt0 + 0) * EBI_KB + kb0) * 1024;
  int cB1 = ((dt0 + 1) * EBI_KB + kb0) * 1024;
  int cB2 = ((dt0 + 2) * EBI_KB + kb0) * 1024;
  int cB3 = ((dt0 + 3) * EBI_KB + kb0) * 1024;
  int vo = lane * 16;

  f32x4 acc[2][4];
#pragma unroll
  for (int a1 = 0; a1 < 2; ++a1)
#pragma unroll
    for (int a2 = 0; a2 < 4; ++a2) { f32x4 z = {0.f, 0.f, 0.f, 0.f}; acc[a1][a2] = z; }

  bf16x8 a00, a01, b00, b01, b02, b03;
  bf16x8 a10, a11, b10, b11, b12, b13;
  bf16x8 a20, a21, b20, b21, b22, b23;

  LOADSET(a00, a01, b00, b01, b02, b03, 0);
  LOADSET(a10, a11, b10, b11, b12, b13, 1);

  int t = 0;
  for (;;) {
    LOADSET(a20, a21, b20, b21, b22, b23, t + 2);
    MMSET(a00, a01, b00, b01, b02, b03);
    if (++t == nt) break;
    LOADSET(a00, a01, b00, b01, b02, b03, t + 2);
    MMSET(a10, a11, b10, b11, b12, b13);
    if (++t == nt) break;
    LOADSET(a10, a11, b10, b11, b12, b13, t + 2);
    MMSET(a20, a21, b20, b21, b22, b23);
    if (++t == nt) break;
  }

  // Epilogue: scatter each q-row to all i with pos_i == q (contiguous via rs)
  const int* rsb = rs + b * RSW;
  const float* xb = x + (size_t)b * NS * ND;
  float* outb = out + (size_t)b * NS * ND;
  int col = lane & 15, rb4 = (lane >> 4) * 4;
#pragma unroll
  for (int nf = 0; nf < 4; ++nf) {
    int dcol = D0w + nf * 16 + col;
    float e0v = emb[dcol];                          // emb row 0 (fp32, exact)
    float eMv = emb[(size_t)(NV - 1) * ND + dcol];  // emb row 2M
#pragma unroll
    for (int mf = 0; mf < 2; ++mf) {
#pragma unroll
      for (int j = 0; j < 4; ++j) {
        int q = Q0w + mf * 16 + rb4 + j;
        if (q >= NP) continue;
        int i0 = rsb[q], i1 = rsb[q + 1];
        if (i0 == i1) continue;
        int cge = (q >= NM) ? rsb[q - NM + 1] : 0;          // #{pos_j <= q-M}
        int cle = (q + NM < NP) ? (NS - rsb[q + NM]) : 0;   // #{pos_j >= q+M}
        float val = (acc[mf][nf][j] + (float)cge * eMv + (float)cle * e0v) * (1.0f / (float)NS);
        for (int i = i0; i < i1; ++i)
          outb[(size_t)i * ND + dcol] = xb[(size_t)i * ND + dcol] + val;
      }
    }
  }
}

extern "C" void kernel_launch(void* const* d_in, const int* in_sizes, int n_in,
                              void* d_out, int out_size, void* d_ws, size_t ws_size,
                              hipStream_t stream) {
  const float* x = (const float*)d_in[0];
  const float* emb = (const float*)d_in[1];
  const int* pos = (const int*)d_in[2];
  float* out = (float*)d_out;

  char* ws = (char*)d_ws;
  unsigned short* HTI = (unsigned short*)(ws);                // 4 x 512KB   = 2,097,152 B
  unsigned short* EBI = (unsigned short*)(ws + 2097152);      // 32x129x1KB  = 4,227,072 B
  int* rs = (int*)(ws + 6324224);                             // 4*3080*4    = 49,280 B
  // total ws use ~6.4 MB

  hipLaunchKernelGGL(k_prep, dim3(1084), dim3(256), 0, stream, pos, emb, HTI, EBI, rs);
  hipLaunchKernelGGL(k4_gemm, dim3(768), dim3(256), 0, stream, HTI, EBI, rs, x, emb, out);
}